// Round 1
// baseline (246.723 us; speedup 1.0000x reference)
//
#include <hip/hip_runtime.h>
#include <hip/hip_bf16.h>
#include <hip/hip_fp16.h>

#define NN 100000      // nodes
#define NE 1000000     // edges
#define NPART 391      // ceil(NN/256)
#define CAP 64         // fixed per-node slot capacity (max degree ~30 for this dist)
#define SPMAX 65536    // spill capacity (edges with rank >= CAP)

// ---------------- workspace layout (4-byte units) ----------------
#define OFF_COUNTS   0              // u32[NN]   (zeroed by k0)
#define OFF_CLCR     100000         // f32[8]
#define OFF_ER1      100008         // f32[NN]
#define OFF_ER2      200008         // f32[NN]
#define OFF_SPN      300008         // u32[1]  spill count
#define OFF_SPD      300012         // u32[SPMAX] spill dst
#define OFF_SPS      365548         // u32[SPMAX] spill src
#define OFF_PFEAT    431084         // float4[NN]  {f0,f1,f2,el1}  (16B aligned)
#define OFF_BSRC     831084         // u32[NN*CAP]  padded rows, 256B each
#define OFF_Z2H      7231084        // half[32*NN] (64B rows; [30]=el2, [31]=0)
#define OFF_PARTS    8831084        // f32[NPART*32]

#define PK2(a,b) __builtin_bit_cast(float, __floats2half2_rn((a),(b)))

// zero hist counts + spill count; compute cl[k]=W1[k,:64]@al1, cr[k]=W1[k,:64]@ar1
__global__ void k0_prep(unsigned* __restrict__ counts, unsigned* __restrict__ spn,
                        const float* __restrict__ W1,
                        const float* __restrict__ al1, const float* __restrict__ ar1,
                        float* __restrict__ clcr) {
    int i = blockIdx.x * blockDim.x + threadIdx.x;
    if (i < NN) counts[i] = 0u;
    if (i == 0) spn[0] = 0u;
    if (blockIdx.x == 0 && threadIdx.x < 64) {
        int j = threadIdx.x;
        float a = al1[j], r = ar1[j];
#pragma unroll
        for (int k = 0; k < 3; ++k) {
            float wv = W1[k*128 + j];
            float vl = wv * a, vr = wv * r;
            for (int off = 32; off > 0; off >>= 1) {
                vl += __shfl_down(vl, off);
                vr += __shfl_down(vr, off);
            }
            if (j == 0) { clcr[k] = vl; clcr[4 + k] = vr; }
        }
    }
}

// fused histogram + direct scatter into fixed-capacity rows (no rank array,
// no prefix scan, no second edge pass); low ids also pack pfeat/er1
__global__ void k1_fused(const int* __restrict__ src, const int* __restrict__ dst,
                         unsigned* __restrict__ counts, unsigned* __restrict__ bsrc,
                         unsigned* __restrict__ spn, unsigned* __restrict__ spd,
                         unsigned* __restrict__ sps,
                         const float* __restrict__ feat, const float* __restrict__ clcr,
                         float4* __restrict__ pfeat, float* __restrict__ er1) {
    int e = blockIdx.x * blockDim.x + threadIdx.x;
    if (e < NE) {
        int d = dst[e];
        unsigned r = atomicAdd(counts + d, 1u);
        if (r < CAP) {
            bsrc[(unsigned)d * CAP + r] = (unsigned)src[e];
        } else {
            unsigned sp = atomicAdd(spn, 1u);
            if (sp < SPMAX) { spd[sp] = (unsigned)d; sps[sp] = (unsigned)src[e]; }
        }
    }
    int n = e;
    if (n < NN) {
        float f0 = feat[n*3], f1 = feat[n*3+1], f2 = feat[n*3+2];
        float el = f0*clcr[0] + f1*clcr[1] + f2*clcr[2];
        float er = f0*clcr[4] + f1*clcr[5] + f2*clcr[6];
        pfeat[n] = make_float4(f0, f1, f2, el);
        er1[n] = er;
    }
}

// per node: gather pfeat[src], recompute p, aggregate; then z2 row via 30 register
// accumulators, fp16 pack, er2
__global__ void k4_node(const unsigned* __restrict__ counts, const unsigned* __restrict__ bsrc,
                        const unsigned* __restrict__ spn, const unsigned* __restrict__ spd,
                        const unsigned* __restrict__ sps,
                        const float4* __restrict__ pfeat, const float* __restrict__ er1,
                        const float* __restrict__ W1, const float* __restrict__ b1,
                        const float* __restrict__ W2, const float* __restrict__ al2,
                        const float* __restrict__ ar2,
                        __half* __restrict__ z2h, float* __restrict__ er2) {
    __shared__ float sW1[192], sb1[64], sW2[1920], sal2[30], sar2[30];
    int tid = threadIdx.x;
    for (int i = tid; i < 192; i += 256) sW1[i] = W1[(i >> 6)*128 + (i & 63)];
    for (int i = tid; i < 1920; i += 256) sW2[i] = W2[(i / 30)*60 + (i % 30)];
    if (tid < 64) sb1[tid] = b1[tid];
    if (tid < 30) { sal2[tid] = al2[tid]; sar2[tid] = ar2[tid]; }
    __syncthreads();
    int n = blockIdx.x * 256 + tid;
    if (n >= NN) return;
    unsigned cnt = counts[n];
    unsigned m = (cnt < CAP) ? cnt : (unsigned)CAP;
    const unsigned* row = bsrc + (size_t)n * CAP;
    float erd = er1[n];
    float s0 = 0.f, s1 = 0.f, s2 = 0.f, sp = 0.f;
    for (unsigned i = 0; i < m; ++i) {
        unsigned s = row[i];
        float4 v = pfeat[s];
        float ee = v.w + erd;
        ee = (ee >= 0.f) ? ee : 0.2f * ee;
        float p = __expf(ee);
        s0 += p * v.x; s1 += p * v.y; s2 += p * v.z; sp += p;
    }
    if (cnt > CAP) {                       // exact spill path (normally never taken)
        unsigned nsp = spn[0]; if (nsp > SPMAX) nsp = SPMAX;
        for (unsigned j = 0; j < nsp; ++j) {
            if (spd[j] == (unsigned)n) {
                float4 v = pfeat[sps[j]];
                float ee = v.w + erd;
                ee = (ee >= 0.f) ? ee : 0.2f * ee;
                float p = __expf(ee);
                s0 += p * v.x; s1 += p * v.y; s2 += p * v.z; sp += p;
            }
        }
    }
    float inv = (sp > 0.f) ? 1.f / sp : 0.f;
    float a0 = s0 * inv, a1 = s1 * inv, a2 = s2 * inv;
    float z[30];
#pragma unroll
    for (int c = 0; c < 30; ++c) z[c] = 0.f;
    for (int j = 0; j < 64; ++j) {
        float rj = fmaxf(a0*sW1[j] + a1*sW1[64 + j] + a2*sW1[128 + j] + sb1[j], 0.f);
#pragma unroll
        for (int c = 0; c < 30; ++c) z[c] += rj * sW2[j*30 + c];
    }
    float sl = 0.f, sr = 0.f;
#pragma unroll
    for (int c = 0; c < 30; ++c) { sl += z[c] * sal2[c]; sr += z[c] * sar2[c]; }
    float4* outp = (float4*)(z2h + (size_t)n * 32);
    outp[0] = make_float4(PK2(z[0],z[1]),  PK2(z[2],z[3]),  PK2(z[4],z[5]),  PK2(z[6],z[7]));
    outp[1] = make_float4(PK2(z[8],z[9]),  PK2(z[10],z[11]),PK2(z[12],z[13]),PK2(z[14],z[15]));
    outp[2] = make_float4(PK2(z[16],z[17]),PK2(z[18],z[19]),PK2(z[20],z[21]),PK2(z[22],z[23]));
    outp[3] = make_float4(PK2(z[24],z[25]),PK2(z[26],z[27]),PK2(z[28],z[29]),PK2(sl, 0.f));
    er2[n] = sr;
}

// per node: gather fp16 z2 rows (64 B, el2 included), softmax-weighted colsum partials
__global__ void k5_layer2(const unsigned* __restrict__ counts, const unsigned* __restrict__ bsrc,
                          const unsigned* __restrict__ spn, const unsigned* __restrict__ spd,
                          const unsigned* __restrict__ sps,
                          const __half* __restrict__ z2h, const float* __restrict__ er2,
                          float* __restrict__ part) {
    int tid = threadIdx.x;
    int lane = tid & 63, wv = tid >> 6;
    int n = blockIdx.x * 256 + tid;
    float acc[32];
#pragma unroll
    for (int q = 0; q < 32; ++q) acc[q] = 0.f;
    if (n < NN) {
        unsigned cnt = counts[n];
        unsigned m = (cnt < CAP) ? cnt : (unsigned)CAP;
        const unsigned* row = bsrc + (size_t)n * CAP;
        float erd = er2[n];
        float sp = 0.f;
#define EDGE_ACC(sidx) { \
            const float4* zr = (const float4*)(z2h + (size_t)(sidx) * 32); \
            float4 r0 = zr[0], r1 = zr[1], r2 = zr[2], r3 = zr[3]; \
            float el = __half2float(__low2half(__builtin_bit_cast(__half2, r3.w))); \
            float ee = el + erd; \
            ee = (ee >= 0.f) ? ee : 0.2f * ee; \
            float p = __expf(ee); \
            sp += p; \
            { float2 f; \
              f = __half22float2(__builtin_bit_cast(__half2, r0.x)); acc[0]  += p*f.x; acc[1]  += p*f.y; \
              f = __half22float2(__builtin_bit_cast(__half2, r0.y)); acc[2]  += p*f.x; acc[3]  += p*f.y; \
              f = __half22float2(__builtin_bit_cast(__half2, r0.z)); acc[4]  += p*f.x; acc[5]  += p*f.y; \
              f = __half22float2(__builtin_bit_cast(__half2, r0.w)); acc[6]  += p*f.x; acc[7]  += p*f.y; \
              f = __half22float2(__builtin_bit_cast(__half2, r1.x)); acc[8]  += p*f.x; acc[9]  += p*f.y; \
              f = __half22float2(__builtin_bit_cast(__half2, r1.y)); acc[10] += p*f.x; acc[11] += p*f.y; \
              f = __half22float2(__builtin_bit_cast(__half2, r1.z)); acc[12] += p*f.x; acc[13] += p*f.y; \
              f = __half22float2(__builtin_bit_cast(__half2, r1.w)); acc[14] += p*f.x; acc[15] += p*f.y; \
              f = __half22float2(__builtin_bit_cast(__half2, r2.x)); acc[16] += p*f.x; acc[17] += p*f.y; \
              f = __half22float2(__builtin_bit_cast(__half2, r2.y)); acc[18] += p*f.x; acc[19] += p*f.y; \
              f = __half22float2(__builtin_bit_cast(__half2, r2.z)); acc[20] += p*f.x; acc[21] += p*f.y; \
              f = __half22float2(__builtin_bit_cast(__half2, r2.w)); acc[22] += p*f.x; acc[23] += p*f.y; \
              f = __half22float2(__builtin_bit_cast(__half2, r3.x)); acc[24] += p*f.x; acc[25] += p*f.y; \
              f = __half22float2(__builtin_bit_cast(__half2, r3.y)); acc[26] += p*f.x; acc[27] += p*f.y; \
              f = __half22float2(__builtin_bit_cast(__half2, r3.z)); acc[28] += p*f.x; acc[29] += p*f.y; \
              f = __half22float2(__builtin_bit_cast(__half2, r3.w)); acc[30] += p*f.x; acc[31] += p*f.y; } }
        for (unsigned i = 0; i < m; ++i) {
            unsigned s = row[i];
            EDGE_ACC(s)
        }
        if (cnt > CAP) {                   // exact spill path (normally never taken)
            unsigned nsp = spn[0]; if (nsp > SPMAX) nsp = SPMAX;
            for (unsigned j = 0; j < nsp; ++j) {
                if (spd[j] == (unsigned)n) { EDGE_ACC(sps[j]) }
            }
        }
#undef EDGE_ACC
        float inv = (sp > 0.f) ? 1.f / sp : 0.f;
#pragma unroll
        for (int q = 0; q < 32; ++q) acc[q] *= inv;
    }
#pragma unroll
    for (int q = 0; q < 32; ++q)
        for (int off = 32; off > 0; off >>= 1) acc[q] += __shfl_down(acc[q], off);
    __shared__ float sh[4][32];
    if (lane == 0) {
#pragma unroll
        for (int q = 0; q < 32; ++q) sh[wv][q] = acc[q];
    }
    __syncthreads();
    if (tid < 32)
        part[blockIdx.x * 32 + tid] = sh[0][tid] + sh[1][tid] + sh[2][tid] + sh[3][tid];
}

// single block: image path, sum partials, a00 = colsum/N + b2[0], concat, log_softmax
__global__ void k6_final(const float* __restrict__ x, const float* __restrict__ vocab,
                         const float* __restrict__ W_lin1, const float* __restrict__ w2,
                         const float* __restrict__ w3, const float* __restrict__ W4,
                         const float* __restrict__ b2, const float* __restrict__ part,
                         float* __restrict__ out) {
    __shared__ float sh[256];
    __shared__ float hvec[70];
    int tid = threadIdx.x;
    int r = tid >> 3, sub = tid & 7;
    float pt = 0.f;
    if (r < 30) {
        for (int k = sub; k < 512; k += 8) pt += W_lin1[r*512 + k] * x[k];
    }
    sh[tid] = pt;
    __syncthreads();
    if (tid < 30) {
        float hi = 0.f;
        for (int i = 0; i < 8; ++i) hi += sh[tid*8 + i];
        float acc = 0.f;
        for (int k = 0; k < 64; ++k) acc += w3[k] / (1.f + __expf(-w2[k] * hi));
        hvec[30 + tid] = 1.f / (1.f + __expf(-acc));
        float cs = 0.f;
        for (int b = 0; b < NPART; ++b) cs += part[b*32 + tid];
        hvec[tid] = cs * (1.0f / (float)NN) + b2[tid];
    }
    if (tid >= 64 && tid < 74) hvec[60 + (tid - 64)] = vocab[tid - 64];
    __syncthreads();
    if (tid == 0) {
        float p0 = 0.f, p1 = 0.f;
        for (int k = 0; k < 70; ++k) {
            p0 += W4[k] * hvec[k];
            p1 += W4[70 + k] * hvec[k];
        }
        float mx = fmaxf(p0, p1);
        float l = logf(__expf(p0 - mx) + __expf(p1 - mx));
        out[0] = p0 - mx - l;
        out[1] = p1 - mx - l;
    }
}

extern "C" void kernel_launch(void* const* d_in, const int* in_sizes, int n_in,
                              void* d_out, int out_size, void* d_ws, size_t ws_size,
                              hipStream_t stream) {
    const float* x      = (const float*)d_in[0];
    const float* feat   = (const float*)d_in[1];
    const float* vocab  = (const float*)d_in[2];
    const int*   src    = (const int*)d_in[3];
    const int*   dst    = (const int*)d_in[4];
    const float* W_lin1 = (const float*)d_in[5];
    const float* w_c2   = (const float*)d_in[6];
    const float* w_c3   = (const float*)d_in[7];
    const float* W_lin4 = (const float*)d_in[8];
    const float* W1     = (const float*)d_in[9];
    const float* al1    = (const float*)d_in[10];
    const float* ar1    = (const float*)d_in[11];
    const float* b1     = (const float*)d_in[12];
    const float* W2     = (const float*)d_in[13];
    const float* al2    = (const float*)d_in[14];
    const float* ar2    = (const float*)d_in[15];
    const float* b2     = (const float*)d_in[16];
    float* out = (float*)d_out;
    float* w = (float*)d_ws;

    unsigned* counts  = (unsigned*)(w + OFF_COUNTS);
    float*    clcr    = w + OFF_CLCR;
    float*    er1     = w + OFF_ER1;
    float*    er2     = w + OFF_ER2;
    unsigned* spn     = (unsigned*)(w + OFF_SPN);
    unsigned* spd     = (unsigned*)(w + OFF_SPD);
    unsigned* sps     = (unsigned*)(w + OFF_SPS);
    float4*   pfeat   = (float4*)(w + OFF_PFEAT);
    unsigned* bsrc    = (unsigned*)(w + OFF_BSRC);
    __half*   z2h     = (__half*)(w + OFF_Z2H);
    float*    part    = w + OFF_PARTS;

    k0_prep<<<NPART, 256, 0, stream>>>(counts, spn, W1, al1, ar1, clcr);
    k1_fused<<<(NE + 255) / 256, 256, 0, stream>>>(src, dst, counts, bsrc, spn, spd, sps,
                                                   feat, clcr, pfeat, er1);
    k4_node<<<NPART, 256, 0, stream>>>(counts, bsrc, spn, spd, sps, pfeat, er1,
                                       W1, b1, W2, al2, ar2, z2h, er2);
    k5_layer2<<<NPART, 256, 0, stream>>>(counts, bsrc, spn, spd, sps, z2h, er2, part);
    k6_final<<<1, 256, 0, stream>>>(x, vocab, W_lin1, w_c2, w_c3, W_lin4, b2, part, out);
}

// Round 2
// 227.101 us; speedup vs baseline: 1.0864x; 1.0864x over previous
//
#include <hip/hip_runtime.h>
#include <hip/hip_bf16.h>
#include <hip/hip_fp16.h>

#define NN 100000      // nodes
#define NE 1000000     // edges
#define NPART 391      // ceil(NN/256)
#define CSTRIDE 16     // counts padded: 1 counter per 64B line (atomic line-lock spread)

// ---------------- workspace layout (4-byte units) ----------------
#define OFF_COUNTS   0              // u32[NN*CSTRIDE]  (only word 0 of each line used)
#define OFF_OFFSETS  1600000        // u32[NN+1]
#define OFF_BSUM     1700004        // u32[NPART]
#define OFF_BOFF     1700396        // u32[NPART]
#define OFF_CLCR     1700788        // f32[8]
#define OFF_ER1      1700796        // f32[NN]
#define OFF_ER2      1800796        // f32[NN]
#define OFF_RANK     1900796        // u32[NE]
#define OFF_PFEAT    2900796        // float4[NN]  {f0,f1,f2,el1}  (16B aligned)
#define OFF_BSRC     3300796        // u32[NE]  compact CSR payload (src only)
#define OFF_Z2H      4300796        // half[32*NN] (64B rows; [30]=el2, [31]=0)
#define OFF_PARTS    5900796        // f32[NPART*32]

#define PK2(a,b) __builtin_bit_cast(float, __floats2half2_rn((a),(b)))

// zero (used words of) hist counts + compute cl[k]=W1[k,:64]@al1, cr[k]=W1[k,:64]@ar1
__global__ void k0_prep(unsigned* __restrict__ counts, const float* __restrict__ W1,
                        const float* __restrict__ al1, const float* __restrict__ ar1,
                        float* __restrict__ clcr) {
    int i = blockIdx.x * blockDim.x + threadIdx.x;
    if (i < NN) counts[(size_t)i * CSTRIDE] = 0u;
    if (blockIdx.x == 0 && threadIdx.x < 64) {
        int j = threadIdx.x;
        float a = al1[j], r = ar1[j];
#pragma unroll
        for (int k = 0; k < 3; ++k) {
            float wv = W1[k*128 + j];
            float vl = wv * a, vr = wv * r;
            for (int off = 32; off > 0; off >>= 1) {
                vl += __shfl_down(vl, off);
                vr += __shfl_down(vr, off);
            }
            if (j == 0) { clcr[k] = vl; clcr[4 + k] = vr; }
        }
    }
}

// histogram of dst into line-padded counters (rank = stable per-node slot);
// low ids also pack pfeat/er1
__global__ void k1_hist_pack(const int* __restrict__ dst, unsigned* __restrict__ counts,
                             unsigned* __restrict__ rank, const float* __restrict__ feat,
                             const float* __restrict__ clcr, float4* __restrict__ pfeat,
                             float* __restrict__ er1) {
    int e = blockIdx.x * blockDim.x + threadIdx.x;
    if (e < NE) rank[e] = atomicAdd(counts + (size_t)dst[e] * CSTRIDE, 1u);
    int n = e;
    if (n < NN) {
        float f0 = feat[n*3], f1 = feat[n*3+1], f2 = feat[n*3+2];
        float el = f0*clcr[0] + f1*clcr[1] + f2*clcr[2];
        float er = f0*clcr[4] + f1*clcr[5] + f2*clcr[6];
        pfeat[n] = make_float4(f0, f1, f2, el);
        er1[n] = er;
    }
}

// scan phase 1: per-block sum of counts
__global__ void kS1(const unsigned* __restrict__ counts, unsigned* __restrict__ bsum) {
    __shared__ unsigned sh[256];
    int t = threadIdx.x;
    int i = blockIdx.x * 256 + t;
    sh[t] = (i < NN) ? counts[(size_t)i * CSTRIDE] : 0u;
    __syncthreads();
    for (int off = 128; off > 0; off >>= 1) {
        if (t < off) sh[t] += sh[t + off];
        __syncthreads();
    }
    if (t == 0) bsum[blockIdx.x] = sh[0];
}

// scan phase 2: single-block exclusive scan of the NPART block sums
__global__ void kS2(const unsigned* __restrict__ bsum, unsigned* __restrict__ boff) {
    __shared__ unsigned sh[512];
    int t = threadIdx.x;
    unsigned v = (t < NPART) ? bsum[t] : 0u;
    sh[t] = v;
    __syncthreads();
    for (int off = 1; off < 512; off <<= 1) {
        unsigned u = (t >= off) ? sh[t - off] : 0u;
        __syncthreads();
        sh[t] += u;
        __syncthreads();
    }
    if (t < NPART) boff[t] = sh[t] - v;   // exclusive
}

// scan phase 3: intra-block exclusive scan + block offset -> offsets[]
__global__ void kS3(const unsigned* __restrict__ counts, const unsigned* __restrict__ boff,
                    unsigned* __restrict__ offsets) {
    __shared__ unsigned sh[256];
    int t = threadIdx.x;
    int i = blockIdx.x * 256 + t;
    unsigned v = (i < NN) ? counts[(size_t)i * CSTRIDE] : 0u;
    sh[t] = v;
    __syncthreads();
    for (int off = 1; off < 256; off <<= 1) {
        unsigned u = (t >= off) ? sh[t - off] : 0u;
        __syncthreads();
        sh[t] += u;
        __syncthreads();
    }
    if (i < NN) offsets[i] = boff[blockIdx.x] + sh[t] - v;
    if (i == NN - 1) offsets[NN] = NE;
}

// per edge: slot = offsets[d] + rank[e]; write only the src index (4 B scatter)
__global__ void k3_scatter(const int* __restrict__ src, const int* __restrict__ dst,
                           const unsigned* __restrict__ offsets, const unsigned* __restrict__ rank,
                           unsigned* __restrict__ bsrc) {
    int e = blockIdx.x * blockDim.x + threadIdx.x;
    if (e >= NE) return;
    bsrc[offsets[dst[e]] + rank[e]] = (unsigned)src[e];
}

// per node: gather pfeat[src] (4-deep MLP unroll), recompute p, aggregate; then z2 row
// via 30 register accumulators, fp16 pack, er2
__global__ void k4_node(const unsigned* __restrict__ offsets, const unsigned* __restrict__ bsrc,
                        const float4* __restrict__ pfeat, const float* __restrict__ er1,
                        const float* __restrict__ W1, const float* __restrict__ b1,
                        const float* __restrict__ W2, const float* __restrict__ al2,
                        const float* __restrict__ ar2,
                        __half* __restrict__ z2h, float* __restrict__ er2) {
    __shared__ float sW1[192], sb1[64], sW2[1920], sal2[30], sar2[30];
    int tid = threadIdx.x;
    for (int i = tid; i < 192; i += 256) sW1[i] = W1[(i >> 6)*128 + (i & 63)];
    for (int i = tid; i < 1920; i += 256) sW2[i] = W2[(i / 30)*60 + (i % 30)];
    if (tid < 64) sb1[tid] = b1[tid];
    if (tid < 30) { sal2[tid] = al2[tid]; sar2[tid] = ar2[tid]; }
    __syncthreads();
    int n = blockIdx.x * 256 + tid;
    if (n >= NN) return;
    unsigned beg = offsets[n], end = offsets[n + 1];
    float erd = er1[n];
    float s0 = 0.f, s1 = 0.f, s2 = 0.f, sp = 0.f;
    unsigned i = beg;
    for (; i + 4 <= end; i += 4) {           // 4 independent gathers in flight
        unsigned sA = bsrc[i], sB = bsrc[i+1], sC = bsrc[i+2], sD = bsrc[i+3];
        float4 vA = pfeat[sA], vB = pfeat[sB], vC = pfeat[sC], vD = pfeat[sD];
        float eA = vA.w + erd; eA = (eA >= 0.f) ? eA : 0.2f * eA; float pA = __expf(eA);
        s0 += pA * vA.x; s1 += pA * vA.y; s2 += pA * vA.z; sp += pA;
        float eB = vB.w + erd; eB = (eB >= 0.f) ? eB : 0.2f * eB; float pB = __expf(eB);
        s0 += pB * vB.x; s1 += pB * vB.y; s2 += pB * vB.z; sp += pB;
        float eC = vC.w + erd; eC = (eC >= 0.f) ? eC : 0.2f * eC; float pC = __expf(eC);
        s0 += pC * vC.x; s1 += pC * vC.y; s2 += pC * vC.z; sp += pC;
        float eD = vD.w + erd; eD = (eD >= 0.f) ? eD : 0.2f * eD; float pD = __expf(eD);
        s0 += pD * vD.x; s1 += pD * vD.y; s2 += pD * vD.z; sp += pD;
    }
    for (; i < end; ++i) {
        unsigned s = bsrc[i];
        float4 v = pfeat[s];
        float ee = v.w + erd;
        ee = (ee >= 0.f) ? ee : 0.2f * ee;
        float p = __expf(ee);
        s0 += p * v.x; s1 += p * v.y; s2 += p * v.z; sp += p;
    }
    float inv = (sp > 0.f) ? 1.f / sp : 0.f;
    float a0 = s0 * inv, a1 = s1 * inv, a2 = s2 * inv;
    float z[30];
#pragma unroll
    for (int c = 0; c < 30; ++c) z[c] = 0.f;
    for (int j = 0; j < 64; ++j) {
        float rj = fmaxf(a0*sW1[j] + a1*sW1[64 + j] + a2*sW1[128 + j] + sb1[j], 0.f);
#pragma unroll
        for (int c = 0; c < 30; ++c) z[c] += rj * sW2[j*30 + c];
    }
    float sl = 0.f, sr = 0.f;
#pragma unroll
    for (int c = 0; c < 30; ++c) { sl += z[c] * sal2[c]; sr += z[c] * sar2[c]; }
    float4* outp = (float4*)(z2h + (size_t)n * 32);
    outp[0] = make_float4(PK2(z[0],z[1]),  PK2(z[2],z[3]),  PK2(z[4],z[5]),  PK2(z[6],z[7]));
    outp[1] = make_float4(PK2(z[8],z[9]),  PK2(z[10],z[11]),PK2(z[12],z[13]),PK2(z[14],z[15]));
    outp[2] = make_float4(PK2(z[16],z[17]),PK2(z[18],z[19]),PK2(z[20],z[21]),PK2(z[22],z[23]));
    outp[3] = make_float4(PK2(z[24],z[25]),PK2(z[26],z[27]),PK2(z[28],z[29]),PK2(sl, 0.f));
    er2[n] = sr;
}

// per node: gather fp16 z2 rows (64 B, el2 included; 2 rows in flight),
// softmax-weighted colsum partials
__global__ void k5_layer2(const unsigned* __restrict__ offsets, const unsigned* __restrict__ bsrc,
                          const __half* __restrict__ z2h, const float* __restrict__ er2,
                          float* __restrict__ part) {
    int tid = threadIdx.x;
    int lane = tid & 63, wv = tid >> 6;
    int n = blockIdx.x * 256 + tid;
    float acc[32];
#pragma unroll
    for (int q = 0; q < 32; ++q) acc[q] = 0.f;
    if (n < NN) {
        unsigned beg = offsets[n], end = offsets[n + 1];
        float erd = er2[n];
        float sp = 0.f;
#define PROC(r0, r1, r2, r3) { \
            float el = __half2float(__low2half(__builtin_bit_cast(__half2, (r3).w))); \
            float ee = el + erd; \
            ee = (ee >= 0.f) ? ee : 0.2f * ee; \
            float p = __expf(ee); \
            sp += p; \
            float2 f; \
            f = __half22float2(__builtin_bit_cast(__half2, (r0).x)); acc[0]  += p*f.x; acc[1]  += p*f.y; \
            f = __half22float2(__builtin_bit_cast(__half2, (r0).y)); acc[2]  += p*f.x; acc[3]  += p*f.y; \
            f = __half22float2(__builtin_bit_cast(__half2, (r0).z)); acc[4]  += p*f.x; acc[5]  += p*f.y; \
            f = __half22float2(__builtin_bit_cast(__half2, (r0).w)); acc[6]  += p*f.x; acc[7]  += p*f.y; \
            f = __half22float2(__builtin_bit_cast(__half2, (r1).x)); acc[8]  += p*f.x; acc[9]  += p*f.y; \
            f = __half22float2(__builtin_bit_cast(__half2, (r1).y)); acc[10] += p*f.x; acc[11] += p*f.y; \
            f = __half22float2(__builtin_bit_cast(__half2, (r1).z)); acc[12] += p*f.x; acc[13] += p*f.y; \
            f = __half22float2(__builtin_bit_cast(__half2, (r1).w)); acc[14] += p*f.x; acc[15] += p*f.y; \
            f = __half22float2(__builtin_bit_cast(__half2, (r2).x)); acc[16] += p*f.x; acc[17] += p*f.y; \
            f = __half22float2(__builtin_bit_cast(__half2, (r2).y)); acc[18] += p*f.x; acc[19] += p*f.y; \
            f = __half22float2(__builtin_bit_cast(__half2, (r2).z)); acc[20] += p*f.x; acc[21] += p*f.y; \
            f = __half22float2(__builtin_bit_cast(__half2, (r2).w)); acc[22] += p*f.x; acc[23] += p*f.y; \
            f = __half22float2(__builtin_bit_cast(__half2, (r3).x)); acc[24] += p*f.x; acc[25] += p*f.y; \
            f = __half22float2(__builtin_bit_cast(__half2, (r3).y)); acc[26] += p*f.x; acc[27] += p*f.y; \
            f = __half22float2(__builtin_bit_cast(__half2, (r3).z)); acc[28] += p*f.x; acc[29] += p*f.y; \
            f = __half22float2(__builtin_bit_cast(__half2, (r3).w)); acc[30] += p*f.x; acc[31] += p*f.y; }
        unsigned i = beg;
        for (; i + 2 <= end; i += 2) {       // 2 rows (8 float4 loads) in flight
            unsigned sA = bsrc[i], sB = bsrc[i+1];
            const float4* zA = (const float4*)(z2h + (size_t)sA * 32);
            const float4* zB = (const float4*)(z2h + (size_t)sB * 32);
            float4 a0 = zA[0], a1 = zA[1], a2 = zA[2], a3 = zA[3];
            float4 b0 = zB[0], b1 = zB[1], b2 = zB[2], b3 = zB[3];
            PROC(a0, a1, a2, a3)
            PROC(b0, b1, b2, b3)
        }
        for (; i < end; ++i) {
            unsigned s = bsrc[i];
            const float4* zr = (const float4*)(z2h + (size_t)s * 32);
            float4 r0 = zr[0], r1 = zr[1], r2 = zr[2], r3 = zr[3];
            PROC(r0, r1, r2, r3)
        }
#undef PROC
        float inv = (sp > 0.f) ? 1.f / sp : 0.f;
#pragma unroll
        for (int q = 0; q < 32; ++q) acc[q] *= inv;
    }
#pragma unroll
    for (int q = 0; q < 32; ++q)
        for (int off = 32; off > 0; off >>= 1) acc[q] += __shfl_down(acc[q], off);
    __shared__ float sh[4][32];
    if (lane == 0) {
#pragma unroll
        for (int q = 0; q < 32; ++q) sh[wv][q] = acc[q];
    }
    __syncthreads();
    if (tid < 32)
        part[blockIdx.x * 32 + tid] = sh[0][tid] + sh[1][tid] + sh[2][tid] + sh[3][tid];
}

// single block: image path, sum partials, a00 = colsum/N + b2[0], concat, log_softmax
__global__ void k6_final(const float* __restrict__ x, const float* __restrict__ vocab,
                         const float* __restrict__ W_lin1, const float* __restrict__ w2,
                         const float* __restrict__ w3, const float* __restrict__ W4,
                         const float* __restrict__ b2, const float* __restrict__ part,
                         float* __restrict__ out) {
    __shared__ float sh[256];
    __shared__ float hvec[70];
    int tid = threadIdx.x;
    int r = tid >> 3, sub = tid & 7;
    float pt = 0.f;
    if (r < 30) {
        for (int k = sub; k < 512; k += 8) pt += W_lin1[r*512 + k] * x[k];
    }
    sh[tid] = pt;
    __syncthreads();
    if (tid < 30) {
        float hi = 0.f;
        for (int i = 0; i < 8; ++i) hi += sh[tid*8 + i];
        float acc = 0.f;
        for (int k = 0; k < 64; ++k) acc += w3[k] / (1.f + __expf(-w2[k] * hi));
        hvec[30 + tid] = 1.f / (1.f + __expf(-acc));
        float cs = 0.f;
        for (int b = 0; b < NPART; ++b) cs += part[b*32 + tid];
        hvec[tid] = cs * (1.0f / (float)NN) + b2[tid];
    }
    if (tid >= 64 && tid < 74) hvec[60 + (tid - 64)] = vocab[tid - 64];
    __syncthreads();
    if (tid == 0) {
        float p0 = 0.f, p1 = 0.f;
        for (int k = 0; k < 70; ++k) {
            p0 += W4[k] * hvec[k];
            p1 += W4[70 + k] * hvec[k];
        }
        float mx = fmaxf(p0, p1);
        float l = logf(__expf(p0 - mx) + __expf(p1 - mx));
        out[0] = p0 - mx - l;
        out[1] = p1 - mx - l;
    }
}

extern "C" void kernel_launch(void* const* d_in, const int* in_sizes, int n_in,
                              void* d_out, int out_size, void* d_ws, size_t ws_size,
                              hipStream_t stream) {
    const float* x      = (const float*)d_in[0];
    const float* feat   = (const float*)d_in[1];
    const float* vocab  = (const float*)d_in[2];
    const int*   src    = (const int*)d_in[3];
    const int*   dst    = (const int*)d_in[4];
    const float* W_lin1 = (const float*)d_in[5];
    const float* w_c2   = (const float*)d_in[6];
    const float* w_c3   = (const float*)d_in[7];
    const float* W_lin4 = (const float*)d_in[8];
    const float* W1     = (const float*)d_in[9];
    const float* al1    = (const float*)d_in[10];
    const float* ar1    = (const float*)d_in[11];
    const float* b1     = (const float*)d_in[12];
    const float* W2     = (const float*)d_in[13];
    const float* al2    = (const float*)d_in[14];
    const float* ar2    = (const float*)d_in[15];
    const float* b2     = (const float*)d_in[16];
    float* out = (float*)d_out;
    float* w = (float*)d_ws;

    unsigned* counts  = (unsigned*)(w + OFF_COUNTS);
    unsigned* offsets = (unsigned*)(w + OFF_OFFSETS);
    unsigned* bsum    = (unsigned*)(w + OFF_BSUM);
    unsigned* boff    = (unsigned*)(w + OFF_BOFF);
    float*    clcr    = w + OFF_CLCR;
    float*    er1     = w + OFF_ER1;
    float*    er2     = w + OFF_ER2;
    unsigned* rank    = (unsigned*)(w + OFF_RANK);
    float4*   pfeat   = (float4*)(w + OFF_PFEAT);
    unsigned* bsrc    = (unsigned*)(w + OFF_BSRC);
    __half*   z2h     = (__half*)(w + OFF_Z2H);
    float*    part    = w + OFF_PARTS;

    k0_prep<<<NPART, 256, 0, stream>>>(counts, W1, al1, ar1, clcr);
    k1_hist_pack<<<(NE + 255) / 256, 256, 0, stream>>>(dst, counts, rank, feat, clcr, pfeat, er1);
    kS1<<<NPART, 256, 0, stream>>>(counts, bsum);
    kS2<<<1, 512, 0, stream>>>(bsum, boff);
    kS3<<<NPART, 256, 0, stream>>>(counts, boff, offsets);
    k3_scatter<<<(NE + 255) / 256, 256, 0, stream>>>(src, dst, offsets, rank, bsrc);
    k4_node<<<NPART, 256, 0, stream>>>(offsets, bsrc, pfeat, er1, W1, b1, W2, al2, ar2, z2h, er2);
    k5_layer2<<<NPART, 256, 0, stream>>>(offsets, bsrc, z2h, er2, part);
    k6_final<<<1, 256, 0, stream>>>(x, vocab, W_lin1, w_c2, w_c3, W_lin4, b2, part, out);
}